// Round 1
// 596.692 us; speedup vs baseline: 1.0257x; 1.0257x over previous
//
#include <hip/hip_runtime.h>

#define Bc 8
#define Sc 256
#define Hc 128
#define HDc 32
#define NHc 4
#define SCALE 0.17677669529663687f

__global__ __launch_bounds__(256, 4) void mmha_kernel(
    const float* __restrict__ hs,
    const float* __restrict__ am,
    const float* __restrict__ abs0,
    const float* __restrict__ abs1,
    const float* __restrict__ rel0,
    const float* __restrict__ rel1,
    const float* __restrict__ Wq, const float* __restrict__ bq,
    const float* __restrict__ Wk, const float* __restrict__ bk,
    const float* __restrict__ Wv, const float* __restrict__ bv,
    const float* __restrict__ Wo, const float* __restrict__ bo,
    float* __restrict__ out)
{
    const int t = threadIdx.x;
    const int bqi = blockIdx.x;        // 0..2047
    const int b = bqi >> 8;
    const int q = bqi & 255;

    __shared__ float hsrow[Hc];
    __shared__ float Qrow[Hc];
    __shared__ float qk_sh[NHc * Hc];   // per-head 128-dim query vectors
    __shared__ float cb_sh[NHc];        // per-head constant score bias (2*Q_h·bkS)
    __shared__ float mask_row[Sc];
    __shared__ float4 red4[256];        // rbar partial reduction (reused per head)
    __shared__ float l_sh[8];
    __shared__ float rbarn[NHc * 132];  // stride 132: 16B-aligned + bank-staggered
    __shared__ float ctx_sh[Hc];

    const size_t rowbase = (size_t)(b * Sc + q) * Hc;

    // ---- stage hidden row + mask row ----
    if (t < Hc) hsrow[t] = hs[rowbase + t];
    mask_row[t] = am[((size_t)(b * Sc) + q) * Sc + t];   // [B,1,S,S]
    __syncthreads();

    // ---- Qrow[t] = bq[t] + hsrow · Wq[:,t]  (coalesced in t) ----
    if (t < Hc) {
        float acc = bq[t];
        #pragma unroll 16
        for (int c = 0; c < Hc; ++c) acc += hsrow[c] * Wq[c * Hc + t];
        Qrow[t] = acc;
    }
    __syncthreads();

    // ---- cbias_h = 2 * sum_d Qrow[h*32+d]*bk[h*32+d] ----
    if (t < Hc) {
        float pv = Qrow[t] * bk[t];
        #pragma unroll
        for (int off = 16; off >= 1; off >>= 1) pv += __shfl_xor(pv, off, 32);
        if ((t & 31) == 0) cb_sh[t >> 5] = 2.0f * pv;
    }
    // ---- qk_h[c'] = sum_d Wk[c', h*32+d] * Q_h[d] ----
    for (int rep = 0; rep < 2; ++rep) {
        int idx = rep * 256 + t;
        int h = idx >> 7, cp = idx & 127;
        const float4* wkr = (const float4*)(Wk + cp * Hc + h * HDc);
        const float4* qr  = (const float4*)(Qrow + h * HDc);
        float acc = 0.f;
        #pragma unroll
        for (int j = 0; j < HDc / 4; ++j) {
            float4 wv = wkr[j];
            float4 qv = qr[j];
            acc += wv.x * qv.x + wv.y * qv.y + wv.z * qv.z + wv.w * qv.w;
        }
        qk_sh[h * Hc + cp] = acc;
    }
    __syncthreads();

    const int c4 = t & 31;      // channel quad (floats 4*c4..4*c4+3)
    const int part = t >> 5;    // row-part 0..7: owns rows row%8==part

    const float4* hs4 = (const float4*)(hs)   + (size_t)b * Sc * (Hc / 4);
    const float4* e0p = (const float4*)(abs0) + (size_t)b * Sc * (Hc / 4);
    const float4* e1p = (const float4*)(abs1) + (size_t)b * Sc * (Hc / 4);
    const float4* e2p = (const float4*)(rel0) + (size_t)(b * Sc + q) * Sc * (Hc / 4);
    const float4* e3p = (const float4*)(rel1) + (size_t)(b * Sc + q) * Sc * (Hc / 4);

    // Per-head persistent state — all indices below are compile-time after
    // full unroll (rule #20: no runtime indexing of register arrays).
    float4 qreg[NHc];
    float  cbr[NHc];
    float4 acc[NHc];
    float  l[NHc];
    #pragma unroll
    for (int h = 0; h < NHc; ++h) {
        qreg[h] = ((const float4*)(qk_sh + h * Hc))[c4];
        cbr[h]  = cb_sh[h];
        acc[h].x = acc[h].y = acc[h].z = acc[h].w = 0.f;
        l[h] = 0.f;
    }

    // ---- FUSED streaming pass: all 4 heads per row ----
    // 5 concurrent 16B loads/iter (hs + abs0/abs1 from L2/L3, rel0/rel1 from
    // HBM) keep the memory pipe continuously fed; 4 independent
    // shuffle-reduce/exp chains per row give ILP to hide shuffle+exp latency.
    #pragma unroll 2
    for (int r = 0; r < 32; ++r) {
        const int row = r * 8 + part;
        const int off = row * (Hc / 4) + c4;
        const float4 a = hs4[off];
        float4 e[NHc];
        e[0] = e0p[off];
        e[1] = e1p[off];
        e[2] = e2p[off];
        e[3] = e3p[off];
        const float m = mask_row[row];
        #pragma unroll
        for (int h = 0; h < NHc; ++h) {
            float4 v;
            v.x = a.x + e[h].x; v.y = a.y + e[h].y;
            v.z = a.z + e[h].z; v.w = a.w + e[h].w;
            float pv = v.x * qreg[h].x + v.y * qreg[h].y
                     + v.z * qreg[h].z + v.w * qreg[h].w;
            #pragma unroll
            for (int o = 16; o >= 1; o >>= 1) pv += __shfl_xor(pv, o, 32);
            const float p = __expf((pv + cbr[h]) * SCALE + m);
            l[h] += p;
            acc[h].x += p * v.x; acc[h].y += p * v.y;
            acc[h].z += p * v.z; acc[h].w += p * v.w;
        }
    }

    // ---- per-head reduction of rbar partials (red4 reused, full unroll) ----
    #pragma unroll
    for (int h = 0; h < NHc; ++h) {
        __syncthreads();            // protect red4 reuse from previous round
        red4[t] = acc[h];
        if (c4 == 0) l_sh[part] = l[h];
        __syncthreads();
        if (t < 32) {
            float4 tot; tot.x = tot.y = tot.z = tot.w = 0.f;
            #pragma unroll
            for (int g = 0; g < 8; ++g) {
                float4 v = red4[g * 32 + t];
                tot.x += v.x; tot.y += v.y; tot.z += v.z; tot.w += v.w;
            }
            float lt = 0.f;
            #pragma unroll
            for (int g = 0; g < 8; ++g) lt += l_sh[g];
            const float inv = 1.0f / lt;
            float4 rv; rv.x = tot.x * inv; rv.y = tot.y * inv;
                       rv.z = tot.z * inv; rv.w = tot.w * inv;
            ((float4*)(rbarn + h * 132))[t] = rv;
        }
    }
    __syncthreads();

    // ---- ctx for ALL heads in one parallel pass (128 threads) ----
    // out channel t = head (t>>5), dim (t&31); Wv column index == t.
    if (t < Hc) {
        const float* rb = rbarn + (t >> 5) * 132;
        float cv = 2.0f * bv[t];
        #pragma unroll 8
        for (int c = 0; c < Hc; ++c) cv += rb[c] * Wv[c * Hc + t];
        ctx_sh[t] = cv;
    }
    __syncthreads();

    // ---- out[b,q,t] = bo[t] + ctx · Wo[:,t] ----
    if (t < Hc) {
        float ov = bo[t];
        #pragma unroll 16
        for (int c = 0; c < Hc; ++c) ov += ctx_sh[c] * Wo[c * Hc + t];
        out[rowbase + t] = ov;
    }
}

extern "C" void kernel_launch(void* const* d_in, const int* in_sizes, int n_in,
                              void* d_out, int out_size, void* d_ws, size_t ws_size,
                              hipStream_t stream) {
    const float* hs = (const float*)d_in[0];
    const float* am = (const float*)d_in[1];
    const float* a0 = (const float*)d_in[2];
    const float* a1 = (const float*)d_in[3];
    const float* r0 = (const float*)d_in[4];
    const float* r1 = (const float*)d_in[5];
    const float* Wq = (const float*)d_in[6];
    const float* bq = (const float*)d_in[7];
    const float* Wk = (const float*)d_in[8];
    const float* bk = (const float*)d_in[9];
    const float* Wv = (const float*)d_in[10];
    const float* bv = (const float*)d_in[11];
    const float* Wo = (const float*)d_in[12];
    const float* bo = (const float*)d_in[13];

    mmha_kernel<<<dim3(Bc * Sc), dim3(256), 0, stream>>>(
        hs, am, a0, a1, r0, r1, Wq, bq, Wk, bk, Wv, bv, Wo, bo, (float*)d_out);
}

// Round 2
// 585.508 us; speedup vs baseline: 1.0453x; 1.0191x over previous
//
#include <hip/hip_runtime.h>

#define Bc 8
#define Sc 256
#define Hc 128
#define HDc 32
#define NHc 4
#define SCALE 0.17677669529663687f

// 16-lane rotate-reduce via DPP (VALU, ~4cy/stage) + one cross-row shuffle.
// Replaces the 5-stage ds_swizzle butterfly (~120cy/stage LDS-pipe latency).
__device__ __forceinline__ float red32(float x) {
    x += __int_as_float(__builtin_amdgcn_update_dpp(
            0, __float_as_int(x), 0x121, 0xF, 0xF, false)); // row_ror:1
    x += __int_as_float(__builtin_amdgcn_update_dpp(
            0, __float_as_int(x), 0x122, 0xF, 0xF, false)); // row_ror:2
    x += __int_as_float(__builtin_amdgcn_update_dpp(
            0, __float_as_int(x), 0x124, 0xF, 0xF, false)); // row_ror:4
    x += __int_as_float(__builtin_amdgcn_update_dpp(
            0, __float_as_int(x), 0x128, 0xF, 0xF, false)); // row_ror:8
    // now every lane of each 16-group holds that group's full sum
    x += __shfl_xor(x, 16, 32);   // combine the two 16-groups (1 LDS op)
    return x;
}

__global__ __launch_bounds__(256, 4) void mmha_kernel(
    const float* __restrict__ hs,
    const float* __restrict__ am,
    const float* __restrict__ abs0,
    const float* __restrict__ abs1,
    const float* __restrict__ rel0,
    const float* __restrict__ rel1,
    const float* __restrict__ Wq, const float* __restrict__ bq,
    const float* __restrict__ Wk, const float* __restrict__ bk,
    const float* __restrict__ Wv, const float* __restrict__ bv,
    const float* __restrict__ Wo, const float* __restrict__ bo,
    float* __restrict__ out)
{
    const int t = threadIdx.x;
    const int bqi = blockIdx.x;        // 0..2047
    const int b = bqi >> 8;
    const int q = bqi & 255;

    // Aliased LDS pool (19.1 KB -> 8 blocks/CU still fit):
    //  phase 1/2: hsrow[128] | Qrow[128] | qk_sh[512] | cb_sh[4] | mask_row[256]
    //  phase 3  : redA = float4[1024] (16KB, overlays the above after barrier)
    //             lA[32] @4096 | rbarn[528] @4128 | ctx[128] @4656
    __shared__ float4 smem4[1196];
    float* sm = (float*)smem4;
    float* hsrow    = sm;
    float* Qrow     = sm + 128;
    float* qk_sh    = sm + 256;
    float* cb_sh    = sm + 768;
    float* mask_row = sm + 772;

    const size_t rowbase = (size_t)(b * Sc + q) * Hc;

    // ---- stage hidden row + mask row ----
    if (t < Hc) hsrow[t] = hs[rowbase + t];
    mask_row[t] = am[((size_t)(b * Sc) + q) * Sc + t];   // [B,1,S,S]
    __syncthreads();

    // ---- Qrow[t] = bq[t] + hsrow · Wq[:,t]  (coalesced in t) ----
    if (t < Hc) {
        float acc = bq[t];
        #pragma unroll 16
        for (int c = 0; c < Hc; ++c) acc += hsrow[c] * Wq[c * Hc + t];
        Qrow[t] = acc;
    }
    __syncthreads();

    // ---- cbias_h = 2 * sum_d Qrow[h*32+d]*bk[h*32+d] ----
    if (t < Hc) {
        float pv = Qrow[t] * bk[t];
        #pragma unroll
        for (int off = 16; off >= 1; off >>= 1) pv += __shfl_xor(pv, off, 32);
        if ((t & 31) == 0) cb_sh[t >> 5] = 2.0f * pv;
    }
    // ---- qk_h[c'] = sum_d Wk[c', h*32+d] * Q_h[d] ----
    for (int rep = 0; rep < 2; ++rep) {
        int idx = rep * 256 + t;
        int h = idx >> 7, cp = idx & 127;
        const float4* wkr = (const float4*)(Wk + cp * Hc + h * HDc);
        const float4* qr  = (const float4*)(Qrow + h * HDc);
        float acc = 0.f;
        #pragma unroll
        for (int j = 0; j < HDc / 4; ++j) {
            float4 wv = wkr[j];
            float4 qv = qr[j];
            acc += wv.x * qv.x + wv.y * qv.y + wv.z * qv.z + wv.w * qv.w;
        }
        qk_sh[h * Hc + cp] = acc;
    }
    __syncthreads();

    const int c4 = t & 31;      // channel quad (floats 4*c4..4*c4+3)
    const int part = t >> 5;    // row-part 0..7: owns rows row%8==part
    const int boff = part * 32 + c4;   // float4 offset of (row=part, quad=c4)

    const float4* hs4 = (const float4*)(hs)   + (size_t)b * Sc * (Hc / 4);
    const float4* e0p = (const float4*)(abs0) + (size_t)b * Sc * (Hc / 4);
    const float4* e1p = (const float4*)(abs1) + (size_t)b * Sc * (Hc / 4);
    const float4* e2p = (const float4*)(rel0) + (size_t)(b * Sc + q) * Sc * (Hc / 4);
    const float4* e3p = (const float4*)(rel1) + (size_t)(b * Sc + q) * Sc * (Hc / 4);

    // per-head state (all literal-indexed after unroll)
    float4 qreg[NHc];
    float  cbs[NHc];
    float4 acc[NHc];
    float  l[NHc];
    #pragma unroll
    for (int h = 0; h < NHc; ++h) {
        qreg[h] = ((const float4*)(qk_sh + h * Hc))[c4];
        cbs[h]  = cb_sh[h] * SCALE;
        acc[h].x = acc[h].y = acc[h].z = acc[h].w = 0.f;
        l[h] = 0.f;
    }

    // ---- software-pipelined streaming pass ----
    // depth-2 buffers for L2/L3-resident streams, depth-4 for HBM rel streams
    float4 A[2], E0[2], E1[2], E2[4], E3[4];
    A[0]  = hs4[boff];        A[1]  = hs4[boff + 256];
    E0[0] = e0p[boff];        E0[1] = e0p[boff + 256];
    E1[0] = e1p[boff];        E1[1] = e1p[boff + 256];
    E2[0] = e2p[boff];        E2[1] = e2p[boff + 256];
    E2[2] = e2p[boff + 512];  E2[3] = e2p[boff + 768];
    E3[0] = e3p[boff];        E3[1] = e3p[boff + 256];
    E3[2] = e3p[boff + 512];  E3[3] = e3p[boff + 768];

#define HEAD(i, f)                                                          \
    {                                                                       \
        float4 v;                                                           \
        v.x = a.x + (f).x; v.y = a.y + (f).y;                               \
        v.z = a.z + (f).z; v.w = a.w + (f).w;                               \
        float pv = red32(v.x * qreg[i].x + v.y * qreg[i].y                  \
                       + v.z * qreg[i].z + v.w * qreg[i].w);                \
        const float p = __expf(pv * SCALE + (cbs[i] + ml));                 \
        l[i] += p;                                                          \
        acc[i].x += p * v.x; acc[i].y += p * v.y;                           \
        acc[i].z += p * v.z; acc[i].w += p * v.w;                           \
    }

#define STEP(K)                                                             \
    do {                                                                    \
        const float4 a  = A[(K) & 1];                                       \
        const float4 f0 = E0[(K) & 1];                                      \
        const float4 f1 = E1[(K) & 1];                                      \
        const float4 f2 = E2[(K) & 3];                                      \
        const float4 f3 = E3[(K) & 3];                                      \
        const float ml = mask_row[(r + (K)) * 8 + part];                    \
        {   /* prefetch L2 streams 2 rows ahead */                          \
            int rn = r + (K) + 2; if (rn > 31) rn = 31;                     \
            const int offn = rn * 256 + boff;                               \
            A[(K) & 1]  = hs4[offn];                                        \
            E0[(K) & 1] = e0p[offn];                                        \
            E1[(K) & 1] = e1p[offn];                                        \
        }                                                                   \
        {   /* prefetch HBM rel streams 4 rows ahead */                     \
            int rn = r + (K) + 4; if (rn > 31) rn = 31;                     \
            const int offn = rn * 256 + boff;                               \
            E2[(K) & 3] = e2p[offn];                                        \
            E3[(K) & 3] = e3p[offn];                                        \
        }                                                                   \
        HEAD(0, f0)                                                         \
        HEAD(1, f1)                                                         \
        HEAD(2, f2)                                                         \
        HEAD(3, f3)                                                         \
    } while (0)

    for (int r = 0; r < 32; r += 4) {
        STEP(0);
        STEP(1);
        STEP(2);
        STEP(3);
    }
#undef STEP
#undef HEAD

    // ---- single-pass epilogue reduction for all 4 heads ----
    __syncthreads();                    // mask_row reads done; reuse pool
    float4* redA = (float4*)sm;         // [4][256] float4
    #pragma unroll
    for (int h = 0; h < NHc; ++h) redA[h * 256 + t] = acc[h];
    if (c4 == 0) {
        #pragma unroll
        for (int h = 0; h < NHc; ++h) sm[4096 + h * 8 + part] = l[h];
    }
    __syncthreads();
    if (t < 128) {
        const int h = t >> 5, j = t & 31;
        float4 tot; tot.x = tot.y = tot.z = tot.w = 0.f;
        #pragma unroll
        for (int g = 0; g < 8; ++g) {
            float4 vv = redA[h * 256 + g * 32 + j];
            tot.x += vv.x; tot.y += vv.y; tot.z += vv.z; tot.w += vv.w;
        }
        float lt = 0.f;
        #pragma unroll
        for (int g = 0; g < 8; ++g) lt += sm[4096 + h * 8 + g];
        const float inv = 1.0f / lt;
        float4 rv; rv.x = tot.x * inv; rv.y = tot.y * inv;
                   rv.z = tot.z * inv; rv.w = tot.w * inv;
        ((float4*)(sm + 4128 + h * 132))[j] = rv;
    }
    __syncthreads();

    // ---- ctx for all heads: out channel t = head (t>>5), dim (t&31) ----
    if (t < Hc) {
        const float* rb = sm + 4128 + (t >> 5) * 132;
        float cv = 2.0f * bv[t];
        #pragma unroll 8
        for (int c = 0; c < Hc; ++c) cv += rb[c] * Wv[c * Hc + t];
        sm[4656 + t] = cv;
    }
    __syncthreads();

    // ---- out[b,q,t] = bo[t] + ctx · Wo[:,t] ----
    if (t < Hc) {
        float ov = bo[t];
        const float* cx = sm + 4656;
        #pragma unroll 16
        for (int c = 0; c < Hc; ++c) ov += cx[c] * Wo[c * Hc + t];
        out[rowbase + t] = ov;
    }
}

extern "C" void kernel_launch(void* const* d_in, const int* in_sizes, int n_in,
                              void* d_out, int out_size, void* d_ws, size_t ws_size,
                              hipStream_t stream) {
    const float* hs = (const float*)d_in[0];
    const float* am = (const float*)d_in[1];
    const float* a0 = (const float*)d_in[2];
    const float* a1 = (const float*)d_in[3];
    const float* r0 = (const float*)d_in[4];
    const float* r1 = (const float*)d_in[5];
    const float* Wq = (const float*)d_in[6];
    const float* bq = (const float*)d_in[7];
    const float* Wk = (const float*)d_in[8];
    const float* bk = (const float*)d_in[9];
    const float* Wv = (const float*)d_in[10];
    const float* bv = (const float*)d_in[11];
    const float* Wo = (const float*)d_in[12];
    const float* bo = (const float*)d_in[13];

    mmha_kernel<<<dim3(Bc * Sc), dim3(256), 0, stream>>>(
        hs, am, a0, a1, r0, r1, Wq, bq, Wk, bk, Wv, bv, Wo, bo, (float*)d_out);
}